// Round 7
// baseline (672.891 us; speedup 1.0000x reference)
//
#include <hip/hip_runtime.h>
#include <hip/hip_bf16.h>
#include <math.h>

#define NN 20000
#define EE 320000
#define NFD 74
#define EFD 12

__device__ __forceinline__ float leakyf(float x) { return x > 0.f ? x : 0.01f * x; }

// ================= batched 128x128-tile fp32 GEMM (8x8/thread) =================
struct GJob {
    const float* A; const float* B; const float* bias; float* C; const int* cnt;
    int a_off; int c_off;
};

// ACT: 0 none, 2 elu with empty-node guard (cnt[gr]>0), 3 leaky-if-col<split
template <int ACT>
__global__ __launch_bounds__(256) void gemm256(
    GJob j0, GJob j1, GJob j2,
    int lda, int ldb, int ldc, int nrows, int K, int M, int split)
{
    GJob jb = (blockIdx.y == 0) ? j0 : ((blockIdx.y == 1) ? j1 : j2);
    const int tiles_m = (M + 127) >> 7;
    const int tn = blockIdx.x / tiles_m;
    const int tm = blockIdx.x % tiles_m;
    const int n0 = tn << 7, m0 = tm << 7;
    __shared__ __align__(16) float As[32][128];
    __shared__ __align__(16) float Bs[32][132];
    const int tid = threadIdx.x;
    const int sr = tid >> 1;            // 0..127 A row
    const int sk = (tid & 1) * 16;      // k offset within 32
    const int br = tid >> 3;            // 0..31 B k-row
    const int bc = (tid & 7) * 16;      // B col
    const int rr = (tid & 15) * 4;      // acc rows rr..rr+3, rr+64..rr+67
    const int cc = (tid >> 4) * 4;      // acc cols cc..cc+3, cc+64..cc+67
    const bool al = ((lda | jb.a_off) & 3) == 0;
    float acc[8][8];
#pragma unroll
    for (int i = 0; i < 8; i++)
#pragma unroll
        for (int j = 0; j < 8; j++) acc[i][j] = 0.f;

    for (int k0 = 0; k0 < K; k0 += 32) {
        {
            const int grow = n0 + sr;
            const bool rok = grow < nrows;
            const float* Ap = jb.A + (size_t)grow * lda + jb.a_off + k0 + sk;
#pragma unroll
            for (int r = 0; r < 16; r += 4) {
                int gj = k0 + sk + r;
                float4 v;
                if (rok && al && gj + 3 < K) {
                    v = *(const float4*)(Ap + r);
                } else {
                    v.x = (rok && gj     < K) ? Ap[r]     : 0.f;
                    v.y = (rok && gj + 1 < K) ? Ap[r + 1] : 0.f;
                    v.z = (rok && gj + 2 < K) ? Ap[r + 2] : 0.f;
                    v.w = (rok && gj + 3 < K) ? Ap[r + 3] : 0.f;
                }
                As[sk + r][sr] = v.x; As[sk + r + 1][sr] = v.y;
                As[sk + r + 2][sr] = v.z; As[sk + r + 3][sr] = v.w;
            }
        }
        {
            const int gj = k0 + br;
            const bool jok = gj < K;
            const float* Bp = jb.B + (size_t)gj * ldb + m0 + bc;
#pragma unroll
            for (int r = 0; r < 16; r += 4) {
                float4 v = make_float4(0.f, 0.f, 0.f, 0.f);
                if (jok) v = *(const float4*)(Bp + r);
                *(float4*)&Bs[br][bc + r] = v;
            }
        }
        __syncthreads();
#pragma unroll
        for (int kk = 0; kk < 32; kk++) {
            float4 a0 = *(const float4*)&As[kk][rr];
            float4 a1 = *(const float4*)&As[kk][rr + 64];
            float4 b0 = *(const float4*)&Bs[kk][cc];
            float4 b1 = *(const float4*)&Bs[kk][cc + 64];
            float av[8] = {a0.x, a0.y, a0.z, a0.w, a1.x, a1.y, a1.z, a1.w};
            float bv[8] = {b0.x, b0.y, b0.z, b0.w, b1.x, b1.y, b1.z, b1.w};
#pragma unroll
            for (int i = 0; i < 8; i++)
#pragma unroll
                for (int j = 0; j < 8; j++)
                    acc[i][j] += av[i] * bv[j];
        }
        __syncthreads();
    }
#pragma unroll
    for (int h = 0; h < 2; h++)
#pragma unroll
    for (int i = 0; i < 4; i++) {
        const int gr = n0 + rr + h * 64 + i;
        if (gr >= nrows) continue;
        bool pos = true;
        if (ACT == 2) pos = jb.cnt[gr] > 0;
        float* Crow = jb.C + (size_t)gr * ldc + jb.c_off;
#pragma unroll
        for (int g2 = 0; g2 < 2; g2++) {
            const int gc = m0 + cc + g2 * 64;
            if (gc >= M) continue;
            float4 v;
            float* a = &acc[h * 4 + i][g2 * 4];
            v.x = a[0] + jb.bias[gc + 0];
            v.y = a[1] + jb.bias[gc + 1];
            v.z = a[2] + jb.bias[gc + 2];
            v.w = a[3] + jb.bias[gc + 3];
            if (ACT == 2) {
                v.x = pos ? (v.x > 0.f ? v.x : (__expf(v.x) - 1.f)) : 0.f;
                v.y = pos ? (v.y > 0.f ? v.y : (__expf(v.y) - 1.f)) : 0.f;
                v.z = pos ? (v.z > 0.f ? v.z : (__expf(v.z) - 1.f)) : 0.f;
                v.w = pos ? (v.w > 0.f ? v.w : (__expf(v.w) - 1.f)) : 0.f;
            }
            if (ACT == 3) {
                if (jb.c_off + gc + 0 < split) v.x = leakyf(v.x);
                if (jb.c_off + gc + 1 < split) v.y = leakyf(v.y);
                if (jb.c_off + gc + 2 < split) v.z = leakyf(v.z);
                if (jb.c_off + gc + 3 < split) v.w = leakyf(v.w);
            }
            *(float4*)(Crow + gc) = v;
        }
    }
}

// ================= weight packing (PK padded to K=80) =================
__global__ void k_pack(
    const float* __restrict__ pn0, const float* __restrict__ pn1, const float* __restrict__ pn2,
    const float* __restrict__ pb0, const float* __restrict__ pb1, const float* __restrict__ pb2,
    const float* __restrict__ pe0, const float* __restrict__ pe1, const float* __restrict__ pe2,
    const float* __restrict__ qb0, const float* __restrict__ qb1, const float* __restrict__ qb2,
    const float* __restrict__ wih, const float* __restrict__ whh,
    float* __restrict__ PK, float* __restrict__ PB, float* __restrict__ WG, float* __restrict__ Z512)
{
    int idx = blockIdx.x * 256 + threadIdx.x;
    const float* pnw[3] = {pn0, pn1, pn2};
    const float* pew[3] = {pe0, pe1, pe2};
    const float* pnb[3] = {pb0, pb1, pb2};
    const float* peb[3] = {qb0, qb1, qb2};
    if (idx < 131072) {
        int r = idx >> 9, c = idx & 511;
        float v;
        if (r < 128) v = (c < 384) ? wih[r * 384 + c] : 0.f;
        else {
            int rr = r - 128;
            if (c < 256) v = whh[rr * 384 + c];
            else if (c < 384) v = 0.f;
            else v = whh[rr * 384 + (c - 128)];
        }
        WG[idx] = v;
    } else if (idx < 131072 + 61440) {
        int t = idx - 131072;
        int r = t / 768, c = t - r * 768;
        int k = (c >> 7) % 3, cc = c & 127;
        PK[t] = (r < NFD) ? ((c < 384) ? pnw[k][r * 128 + cc] : pew[k][r * 128 + cc]) : 0.f;
    } else if (idx < 131072 + 61440 + 768) {
        int c = idx - (131072 + 61440);
        int k = (c >> 7) % 3, cc = c & 127;
        PB[c] = (c < 384) ? pnb[k][cc] : peb[k][cc];
    } else if (idx < 131072 + 61440 + 768 + 512) {
        Z512[idx - (131072 + 61440 + 768)] = 0.f;
    }
}

// nf [N,74] -> PA [N,80] zero-padded (enables aligned float4 staging in gemm)
__global__ void k_prep(const float* __restrict__ nf, float* __restrict__ PA)
{
    int idx = blockIdx.x * 256 + threadIdx.x;
    if (idx < NN * 80) {
        int n = idx / 80, c = idx - n * 80;
        PA[idx] = (c < NFD) ? nf[n * NFD + c] : 0.f;
    }
}

// ================= CSR build (no prefix scan: disjoint ranges suffice) =========
__global__ void k_count(const int* __restrict__ dst, int* __restrict__ cnt)
{
    int e = blockIdx.x * 256 + threadIdx.x;
    if (e < EE) atomicAdd(&cnt[dst[e]], 1);
}

__global__ void k_off(const int* __restrict__ cnt, int* __restrict__ offs,
                      int* __restrict__ cur, int* __restrict__ total)
{
    int n = blockIdx.x * 256 + threadIdx.x;
    if (n < NN) {
        int c = cnt[n];
        int o = atomicAdd(total, c);
        offs[n] = o;
        cur[n] = o;
    }
}

__global__ void k_fill(const int* __restrict__ dst, const int* __restrict__ src,
                       const float* __restrict__ ef,
                       int* __restrict__ cur, int* __restrict__ csr_src,
                       float* __restrict__ EFC)
{
    int e = blockIdx.x * 256 + threadIdx.x;
    if (e < EE) {
        int p = atomicAdd(&cur[dst[e]], 1);
        csr_src[p] = src[e];
        const float4* s = (const float4*)(ef + (size_t)e * 12);
        float4* d = (float4*)(EFC + (size_t)p * 12);
        float4 v0 = s[0], v1 = s[1], v2 = s[2];
        d[0] = v0; d[1] = v1; d[2] = v2;
    }
}

// ================= fused edge pipeline: wave per node, branch = blockIdx.y =====
// lane = er(4 edge slots) x cg(16 ch-groups of 8 ch). Weights in LDS.
// Per iter: x = sum_j ef_j*W_j (LDS) issued AFTER the Pn gather, so the gather's
// latency hides under the j-loop; next slot's sn/ef prefetched one iter ahead.
__global__ __launch_bounds__(256) void k_fused(
    const float* __restrict__ HP,   // [N,768]: hv | Pn
    const float* __restrict__ EFC,  // CSR-ordered edge feats [E,12]
    const float* __restrict__ pw0, const float* __restrict__ pw1, const float* __restrict__ pw2,
    const float* __restrict__ v0, const float* __restrict__ v1, const float* __restrict__ v2,
    const float* __restrict__ b20, const float* __restrict__ b21, const float* __restrict__ b22,
    const int* __restrict__ csr_src,
    const int* __restrict__ offs, const int* __restrict__ cnt,
    float* __restrict__ AX)
{
    const int k = blockIdx.y;
    __shared__ __align__(16) float sW[12 * 128];
    const float* pw = (k == 0) ? pw0 : (k == 1) ? pw1 : pw2;
    const float* vv = (k == 0) ? v0 : (k == 1) ? v1 : v2;
    for (int idx = threadIdx.x; idx < 12 * 128; idx += 256)
        sW[idx] = pw[NFD * 128 + idx];
    __syncthreads();

    const int n = blockIdx.x * 4 + (threadIdx.x >> 6);
    if (n >= NN) return;
    const int lane = threadIdx.x & 63;
    const int er = lane >> 4, cg = lane & 15;
    const int c4 = cg * 4;
    const float b2 = ((k == 0) ? b20 : (k == 1) ? b21 : b22)[0];

    const int o0 = offs[n];
    const int deg = cnt[n];
    float* arow = AX + (size_t)n * 384 + k * 128;
    if (deg == 0) {
        if (er == 0) {
            *(float4*)(arow + c4) = make_float4(0.f, 0.f, 0.f, 0.f);
            *(float4*)(arow + 64 + c4) = make_float4(0.f, 0.f, 0.f, 0.f);
        }
        return;
    }

    float4 wb0 = *(const float4*)(vv + 128 + c4);
    float4 wb1 = *(const float4*)(vv + 128 + 64 + c4);

    // qa = hv_k[n] . w2a  (reduce over the 16 cg lanes)
    float qa;
    {
        float4 wa0 = *(const float4*)(vv + c4);
        float4 wa1 = *(const float4*)(vv + 64 + c4);
        const float* hr = HP + (size_t)n * 768 + k * 128;
        float4 h0 = *(const float4*)(hr + c4);
        float4 h1 = *(const float4*)(hr + 64 + c4);
        qa = h0.x * wa0.x + h0.y * wa0.y + h0.z * wa0.z + h0.w * wa0.w
           + h1.x * wa1.x + h1.y * wa1.y + h1.z * wa1.z + h1.w * wa1.w;
#pragma unroll
        for (int d = 1; d < 16; d <<= 1) qa += __shfl_xor(qa, d, 64);
    }

    const float* Pn = HP + 384 + (size_t)k * 128;
    float4 a0 = make_float4(0.f, 0.f, 0.f, 0.f);
    float4 a1 = make_float4(0.f, 0.f, 0.f, 0.f);
    float s = 0.f;

    // prologue: slot group 0
    int q0 = o0 + (er < deg ? er : 0);
    int sn_c = csr_src[q0];
    const float4* ep0 = (const float4*)(EFC + (size_t)q0 * 12);
    float4 ec0 = ep0[0], ec1 = ep0[1], ec2 = ep0[2];

    for (int b = 0; b < deg; b += 4) {
        const bool on = (b + er) < deg;
        // issue Pn gather for current slot (consumed after the j-loop)
        const float* pr = Pn + (size_t)sn_c * 768;
        float4 px0 = *(const float4*)(pr + c4);
        float4 px1 = *(const float4*)(pr + 64 + c4);
        // prefetch next slot's sn/ef (position-indexed, no dependence)
        int bn = b + 4;
        int sn_n = sn_c;
        float4 en0 = ec0, en1 = ec1, en2 = ec2;
        if (bn < deg) {
            int pn_pos = bn + er;
            int qn = o0 + (pn_pos < deg ? pn_pos : 0);
            sn_n = csr_src[qn];
            const float4* epn = (const float4*)(EFC + (size_t)qn * 12);
            en0 = epn[0]; en1 = epn[1]; en2 = epn[2];
        }
        // x = sum_j ef_j * W_j  (weights from LDS)
        float ef[12] = {ec0.x, ec0.y, ec0.z, ec0.w, ec1.x, ec1.y, ec1.z, ec1.w,
                        ec2.x, ec2.y, ec2.z, ec2.w};
        float4 x0 = make_float4(0.f, 0.f, 0.f, 0.f);
        float4 x1 = make_float4(0.f, 0.f, 0.f, 0.f);
#pragma unroll
        for (int j = 0; j < 12; j++) {
            float e = ef[j];
            float4 w0 = *(const float4*)&sW[j * 128 + c4];
            float4 w1 = *(const float4*)&sW[j * 128 + 64 + c4];
            x0.x += e * w0.x; x0.y += e * w0.y; x0.z += e * w0.z; x0.w += e * w0.w;
            x1.x += e * w1.x; x1.y += e * w1.y; x1.z += e * w1.z; x1.w += e * w1.w;
        }
        // add gathered Pn row, activation
        x0.x = leakyf(x0.x + px0.x); x0.y = leakyf(x0.y + px0.y);
        x0.z = leakyf(x0.z + px0.z); x0.w = leakyf(x0.w + px0.w);
        x1.x = leakyf(x1.x + px1.x); x1.y = leakyf(x1.y + px1.y);
        x1.z = leakyf(x1.z + px1.z); x1.w = leakyf(x1.w + px1.w);
        float dd = x0.x * wb0.x + x0.y * wb0.y + x0.z * wb0.z + x0.w * wb0.w
                 + x1.x * wb1.x + x1.y * wb1.y + x1.z * wb1.z + x1.w * wb1.w;
#pragma unroll
        for (int d = 1; d < 16; d <<= 1) dd += __shfl_xor(dd, d, 64);
        float ex = on ? __expf(leakyf(qa + dd + b2)) : 0.f;
        a0.x += ex * x0.x; a0.y += ex * x0.y; a0.z += ex * x0.z; a0.w += ex * x0.w;
        a1.x += ex * x1.x; a1.y += ex * x1.y; a1.z += ex * x1.z; a1.w += ex * x1.w;
        s += ex;
        // rotate prefetch
        sn_c = sn_n; ec0 = en0; ec1 = en1; ec2 = en2;
    }
#pragma unroll
    for (int d = 16; d < 64; d <<= 1) {
        a0.x += __shfl_xor(a0.x, d, 64); a0.y += __shfl_xor(a0.y, d, 64);
        a0.z += __shfl_xor(a0.z, d, 64); a0.w += __shfl_xor(a0.w, d, 64);
        a1.x += __shfl_xor(a1.x, d, 64); a1.y += __shfl_xor(a1.y, d, 64);
        a1.z += __shfl_xor(a1.z, d, 64); a1.w += __shfl_xor(a1.w, d, 64);
        s += __shfl_xor(s, d, 64);
    }
    if (er == 0) {
        float inv = 1.f / s;
        a0.x *= inv; a0.y *= inv; a0.z *= inv; a0.w *= inv;
        a1.x *= inv; a1.y *= inv; a1.z *= inv; a1.w *= inv;
        *(float4*)(arow + c4) = a0;
        *(float4*)(arow + 64 + c4) = a1;
    }
}

// ================= fused GRU gates + relu =================
__global__ void k_gru2(const float* __restrict__ G, const float* __restrict__ X,
                       const float* __restrict__ bih, const float* __restrict__ bhh,
                       float* __restrict__ out)
{
    int idx = blockIdx.x * 256 + threadIdx.x;
    if (idx >= NN * 128) return;
    int n = idx >> 7, c = idx & 127;
    const float* g = G + (size_t)n * 512;
    float r = 1.f / (1.f + __expf(-(g[c] + bih[c] + bhh[c])));
    float z = 1.f / (1.f + __expf(-(g[128 + c] + bih[128 + c] + bhh[128 + c])));
    float nv = tanhf(g[256 + c] + bih[256 + c] + r * (g[384 + c] + bhh[256 + c]));
    float h = X[(size_t)n * 256 + 128 + c];
    float v = (1.f - z) * nv + z * h;
    out[idx] = v > 0.f ? v : 0.f;
}

extern "C" void kernel_launch(void* const* d_in, const int* in_sizes, int n_in,
                              void* d_out, int out_size, void* d_ws, size_t ws_size,
                              hipStream_t stream)
{
    const float* nf = (const float*)d_in[0];
    const float* ef = (const float*)d_in[1];
    const float *pn_w[3], *pn_b[3], *pe1_w[3], *pe1_b[3], *pe2_w[3], *pe2_b[3], *et_w[3], *et_b[3];
    for (int k = 0; k < 3; k++) {
        int b = 2 + k * 8;
        pn_w[k] = (const float*)d_in[b + 0]; pn_b[k] = (const float*)d_in[b + 1];
        pe1_w[k] = (const float*)d_in[b + 2]; pe1_b[k] = (const float*)d_in[b + 3];
        pe2_w[k] = (const float*)d_in[b + 4]; pe2_b[k] = (const float*)d_in[b + 5];
        et_w[k] = (const float*)d_in[b + 6]; et_b[k] = (const float*)d_in[b + 7];
    }
    const float* mca_w = (const float*)d_in[26]; const float* mca_b = (const float*)d_in[27];
    const float* mcn_w = (const float*)d_in[28]; const float* mcn_b = (const float*)d_in[29];
    const float* wih = (const float*)d_in[30]; const float* whh = (const float*)d_in[31];
    const float* bih = (const float*)d_in[32]; const float* bhh = (const float*)d_in[33];
    const int* src = (const int*)d_in[34];
    const int* dst = (const int*)d_in[35];

    float* W = (float*)d_ws;
    size_t o = 0;
    float* HP = W + o;   o += (size_t)NN * 768;   // hv | Pn->CTX; reused as G [N,512]
    float* AX = W + o;   o += (size_t)NN * 384;   // weighted sums; reused as X [N,256]
    float* EFC = W + o;  o += (size_t)EE * 12;    // CSR edge feats; head aliased as PA [N,80]
    float* PK = W + o;   o += 80 * 768;
    float* PB = W + o;   o += 768;
    float* WG = W + o;   o += 256 * 512;
    float* Z512 = W + o; o += 512;
    int* cnt = (int*)(W + o);
    int* total = cnt + NN;
    int* offs = total + 1;
    int* cur = offs + NN;
    int* csr_src = cur + NN;
    size_t need = o * 4 + (size_t)(NN * 3 + 1 + EE) * 4;
    if (ws_size < need) return;  // fail loudly (out stays poisoned)

    float* PA = EFC;  // [N,80] padded nf; dead before k_fill overwrites EFC
    float* Xb = AX;   // [N,256]
    float* Gb = HP;   // [N,512]

    hipMemsetAsync(cnt, 0, (NN + 1) * sizeof(int), stream);  // cnt + total

    dim3 blk(256);
    k_pack<<<757, blk, 0, stream>>>(
        pn_w[0], pn_w[1], pn_w[2], pn_b[0], pn_b[1], pn_b[2],
        pe1_w[0], pe1_w[1], pe1_w[2], pe1_b[0], pe1_b[1], pe1_b[2],
        wih, whh, PK, PB, WG, Z512);
    k_prep<<<(NN * 80 + 255) / 256, blk, 0, stream>>>(nf, PA);

    const int rt = (NN + 127) / 128;   // 157

    // HP = [leaky(PA@pnw+b) | PA@pe1w+b]   (K=80 aligned)
    {
        GJob j = {PA, PK, PB, HP, nullptr, 0, 0};
        gemm256<3><<<dim3(rt * 6, 1), blk, 0, stream>>>(j, j, j, 80, 768, 768, NN, 80, 768, 384);
    }

    k_count<<<(EE + 255) / 256, blk, 0, stream>>>(dst, cnt);
    k_off<<<(NN + 255) / 256, blk, 0, stream>>>(cnt, offs, cur, total);
    k_fill<<<(EE + 255) / 256, blk, 0, stream>>>(dst, src, ef, cur, csr_src, EFC);

    // fused: qa + he1k + logits + softmax + weighted aggregation
    k_fused<<<dim3(NN / 4, 3), blk, 0, stream>>>(HP, EFC,
        pe1_w[0], pe1_w[1], pe1_w[2], pe2_w[0], pe2_w[1], pe2_w[2],
        pe2_b[0], pe2_b[1], pe2_b[2], csr_src, offs, cnt, AX);

    // ctx_k = elu(AX_k @ et_w + b) -> HP cols 384.. (batched over k, empty-node guard)
    {
        GJob j0 = {AX, et_w[0], et_b[0], HP, cnt, 0 * 128, 384 + 0 * 128};
        GJob j1 = {AX, et_w[1], et_b[1], HP, cnt, 1 * 128, 384 + 1 * 128};
        GJob j2 = {AX, et_w[2], et_b[2], HP, cnt, 2 * 128, 384 + 2 * 128};
        gemm256<2><<<dim3(rt, 3), blk, 0, stream>>>(j0, j1, j2, 384, 128, 768, NN, 128, 128, 0);
    }
    // X[:,0:128] = ctx@mca_w+b ; X[:,128:256] = hv@mcn_w+b (batched)
    {
        GJob j0 = {HP, mca_w, mca_b, Xb, nullptr, 384, 0};
        GJob j1 = {HP, mcn_w, mcn_b, Xb, nullptr, 0, 128};
        gemm256<0><<<dim3(rt, 2), blk, 0, stream>>>(j0, j1, j1, 768, 128, 256, NN, 384, 128, 0);
    }
    // G = X @ WG  (r|z|in|hn)
    {
        GJob j = {Xb, WG, Z512, Gb, nullptr, 0, 0};
        gemm256<0><<<dim3(rt * 4, 1), blk, 0, stream>>>(j, j, j, 256, 512, 512, NN, 256, 512, 0);
    }

    k_gru2<<<(NN * 128 + 255) / 256, blk, 0, stream>>>(Gb, Xb, bih, bhh, (float*)d_out);
}